// Round 2
// baseline (6300.636 us; speedup 1.0000x reference)
//
#include <hip/hip_runtime.h>
#include <math.h>

#define B_   2
#define S_   4096
#define IN_  2048
#define ST_  2048
#define H_   16
#define D_   128
#define C3   6144   // 3*STATE

typedef __bf16 bf16x8 __attribute__((ext_vector_type(8)));
typedef float  f32x4  __attribute__((ext_vector_type(4)));

__device__ __forceinline__ float bf2f(unsigned short u) {
  union { unsigned int i; float f; } c; c.i = ((unsigned int)u) << 16; return c.f;
}
__device__ __forceinline__ unsigned short f2b_rtne(float f) {
  unsigned int x = __builtin_bit_cast(unsigned int, f);
  unsigned int r = (x + 0x7fffu + ((x >> 16) & 1u)) >> 16;
  return (unsigned short)r;
}
__device__ __forceinline__ float fast_sigmoid(float x) {
  return 1.0f / (1.0f + __expf(-x));
}
__device__ __forceinline__ float fast_tanh(float x) {
  float e = __expf(2.0f * x);
  return 1.0f - 2.0f / (e + 1.0f);
}

__device__ __forceinline__ void gload_lds16(const void* g, void* l) {
  __builtin_amdgcn_global_load_lds(
      (const __attribute__((address_space(1))) void*)g,
      (__attribute__((address_space(3))) void*)l, 16, 0, 0);
}

// ---------------- f32 -> bf16 convert ----------------
__global__ void f2b4(const float* __restrict__ in, unsigned short* __restrict__ out, int n4) {
  int i = blockIdx.x * 256 + threadIdx.x;
  if (i < n4) {
    f32x4 v = *(const f32x4*)(in + (size_t)i * 4);
    ushort4 o;
    o.x = f2b_rtne(v[0]); o.y = f2b_rtne(v[1]);
    o.z = f2b_rtne(v[2]); o.w = f2b_rtne(v[3]);
    *(ushort4*)(out + (size_t)i * 4) = o;
  }
}

// ---------------- bf16 GEMM: C[M][N] = A[M][K] * Bt[N][K]^T  (m97 structure) ----------------
template<bool TANH_BIAS, typename OutT>
__global__ __launch_bounds__(256, 2)
void gemm_bt(const unsigned short* __restrict__ A, const unsigned short* __restrict__ Bt,
             const float* __restrict__ bias, OutT* __restrict__ Cout,
             int M, int N, int K) {
  __shared__ __align__(16) unsigned short As[2][128 * 32];
  __shared__ __align__(16) unsigned short Bs[2][128 * 32];
  const int t    = threadIdx.x;
  const int wave = t >> 6, lane = t & 63;
  const int wm   = wave >> 1, wn = wave & 1;
  const int bm   = blockIdx.y * 128, bn = blockIdx.x * 128;

  auto stage = [&](int buf, int kt) {
#pragma unroll
    for (int p = 0; p < 2; ++p) {
      int unit = p * 256 + t;          // 16-byte unit, 512 units = 8KB tile
      int elem = unit * 8;             // bf16 element index
      int row  = elem >> 5;            // /32
      int col  = elem & 31;
      gload_lds16(A  + (size_t)(bm + row) * K + kt * 32 + col, &As[buf][elem]);
      gload_lds16(Bt + (size_t)(bn + row) * K + kt * 32 + col, &Bs[buf][elem]);
    }
  };

  f32x4 acc[4][4] = {};
  int cur = 0;
  stage(0, 0);
  __syncthreads();
  const int NT = K >> 5;
  for (int kt = 0; kt < NT; ++kt) {
    if (kt + 1 < NT) stage(cur ^ 1, kt + 1);
    const int kk = (lane >> 4) * 8;
    bf16x8 a[4], b[4];
#pragma unroll
    for (int m = 0; m < 4; ++m) {
      int row = wm * 64 + m * 16 + (lane & 15);
      a[m] = *(const bf16x8*)&As[cur][row * 32 + kk];
    }
#pragma unroll
    for (int n = 0; n < 4; ++n) {
      int col = wn * 64 + n * 16 + (lane & 15);
      b[n] = *(const bf16x8*)&Bs[cur][col * 32 + kk];
    }
#pragma unroll
    for (int m = 0; m < 4; ++m)
#pragma unroll
      for (int n = 0; n < 4; ++n)
        acc[m][n] = __builtin_amdgcn_mfma_f32_16x16x32_bf16(a[m], b[n], acc[m][n], 0, 0, 0);
    __syncthreads();
    cur ^= 1;
  }

#pragma unroll
  for (int n = 0; n < 4; ++n) {
    int col = bn + wn * 64 + n * 16 + (lane & 15);
    float bv = TANH_BIAS ? bias[col] : 0.0f;
#pragma unroll
    for (int m = 0; m < 4; ++m) {
      int row0 = bm + wm * 64 + m * 16 + (lane >> 4) * 4;
#pragma unroll
      for (int j = 0; j < 4; ++j) {
        float v = acc[m][n][j];
        if (TANH_BIAS) {
          v = fast_tanh(v + bv);
          ((unsigned short*)Cout)[(size_t)(row0 + j) * N + col] = f2b_rtne(v);
        } else {
          ((float*)Cout)[(size_t)(row0 + j) * N + col] = v;
        }
      }
    }
  }
}

// ---------------- fused conv + sequential GRU scan: one workgroup per (b,h) ----------------
// 256 threads. Phase A: thread t<128 computes r-gate for element t; t>=128 computes
// f-gate for element t-128 (each a full 128-dot against h, weights in registers).
// Phase B: thread pair (2e,2e+1) computes cand[e] (64-dot halves + shfl), even thread
// applies the h-update and emits y. Conv K=4 is fused as a per-channel register window.
__global__ __launch_bounds__(256, 1)
void scan_kernel(const unsigned short* __restrict__ z,
                 const float* __restrict__ cw, const float* __restrict__ cb,
                 const float* __restrict__ sw,
                 unsigned short* __restrict__ y) {
  const int blk = blockIdx.x;       // 0..31
  const int b = blk >> 4, h = blk & 15;
  const int t = threadIdx.x;
  __shared__ __align__(16) float hS[128];
  __shared__ __align__(16) float rhS[128];
  __shared__ __align__(16) float fS[128];

  const float FAC = 1.0f / sqrtf(2176.0f);
  const bool isR = (t < 128);
  const int e = t & 127;
  // phase-A weight column: r-gate (rw = sw[32+h]) or f-gate (fw = sw[16+h])
  const int gateM = isR ? (32 + h) : (16 + h);
  float wA[128];
  {
    const float* wp = sw + (size_t)gateM * (D_ * D_) + e;
#pragma unroll
    for (int d = 0; d < 128; ++d) wA[d] = wp[(size_t)d * 128] * FAC;
  }
  // phase-B weight half-column: cand (w = sw[h]); pair (t, t^1) covers one output e2
  const int e2 = t >> 1, half = t & 1;
  float wB[64];
  {
    const float* wp = sw + (size_t)h * (D_ * D_) + (size_t)(half * 64) * 128 + e2;
#pragma unroll
    for (int j = 0; j < 64; ++j) wB[j] = wp[(size_t)j * 128] * FAC;
  }

  // conv taps + biases for this thread's gate channel and i channel
  const int chg = isR ? (2 * ST_ + h * 128 + e) : (ST_ + h * 128 + e);
  const int chi = h * 128 + e2;
  const float cwg0 = cw[chg * 4 + 0], cwg1 = cw[chg * 4 + 1],
              cwg2 = cw[chg * 4 + 2], cwg3 = cw[chg * 4 + 3], cbg = cb[chg];
  const float cwi0 = cw[chi * 4 + 0], cwi1 = cw[chi * 4 + 1],
              cwi2 = cw[chi * 4 + 2], cwi3 = cw[chi * 4 + 3], cbi = cb[chi];

  const unsigned short* zg = z + (size_t)b * S_ * C3 + chg;
  const unsigned short* zi = z + (size_t)b * S_ * C3 + chi;
  unsigned short* yp = y + (size_t)b * S_ * ST_ + h * 128;

  // sliding windows: g3 = z[s], g2 = z[s-1], ...
  float g0 = 0.f, g1 = 0.f, g2 = 0.f, g3 = bf2f(zg[0]);
  float i0 = 0.f, i1 = 0.f, i2 = 0.f, i3 = bf2f(zi[0]);
  float gn = bf2f(zg[C3]);   // z[1]
  float in_ = bf2f(zi[C3]);

  if (t < 128) hS[t] = 0.0f;
  __syncthreads();

  for (int st = 0; st < S_; ++st) {
    // prefetch z[st+2] (2 iterations ahead of use)
    float gnn = 0.f, inn = 0.f;
    if (st + 2 < S_) {
      gnn = bf2f(zg[(size_t)(st + 2) * C3]);
      inn = bf2f(zi[(size_t)(st + 2) * C3]);
    }
    const float gate_in = (g0 * cwg0 + g1 * cwg1 + g2 * cwg2 + g3 * cwg3 + cbg) * FAC;
    const float i_in    = (i0 * cwi0 + i1 * cwi1 + i2 * cwi2 + i3 * cwi3 + cbi) * FAC;

    // phase A: gate = sigmoid(gate_in + h . wA)
    float a0 = 0.f, a1 = 0.f, a2 = 0.f, a3 = 0.f;
#pragma unroll
    for (int d = 0; d < 128; d += 4) {
      f32x4 hv = *(const f32x4*)&hS[d];
      a0 += hv[0] * wA[d + 0];
      a1 += hv[1] * wA[d + 1];
      a2 += hv[2] * wA[d + 2];
      a3 += hv[3] * wA[d + 3];
    }
    float g = fast_sigmoid(((a0 + a1) + (a2 + a3)) + gate_in);
    if (isR) rhS[e] = g * hS[e];   // r*h
    else     fS[e]  = g;           // f gate
    __syncthreads();

    // phase B: cand = tanh(i_in + (r*h) . wB), pair-split over d
    float c0 = 0.f, c1 = 0.f;
#pragma unroll
    for (int j = 0; j < 64; j += 2) {
      c0 += rhS[half * 64 + j + 0] * wB[j + 0];
      c1 += rhS[half * 64 + j + 1] * wB[j + 1];
    }
    float cacc = c0 + c1;
    cacc += __shfl_xor(cacc, 1);
    float cand = fast_tanh(cacc + i_in);
    if (half == 0) {
      float f = fS[e2];
      float hOld = hS[e2];
      float hNew = f * hOld + (1.0f - f) * cand;
      hS[e2] = hNew;
      yp[(size_t)st * ST_ + e2] = f2b_rtne(hNew);
    }
    __syncthreads();

    g0 = g1; g1 = g2; g2 = g3; g3 = gn; gn = gnn;
    i0 = i1; i1 = i2; i2 = i3; i3 = in_; in_ = inn;
  }
}

extern "C" void kernel_launch(void* const* d_in, const int* in_sizes, int n_in,
                              void* d_out, int out_size, void* d_ws, size_t ws_size,
                              hipStream_t stream) {
  const float* x      = (const float*)d_in[0];
  const float* w_in   = (const float*)d_in[1];
  const float* b_in   = (const float*)d_in[2];
  const float* conv_w = (const float*)d_in[3];
  const float* conv_b = (const float*)d_in[4];
  const float* sw     = (const float*)d_in[5];
  const float* w_out  = (const float*)d_in[6];
  float* out = (float*)d_out;

  // Compact workspace layout (peak 152 MiB):
  //   z_b    [0,          100663296)   8192 x 6144 bf16  (gemm1 out, scan in)
  //   xb     [100663296,  134217728)   x as bf16         (dead after gemm1)
  //   w_in_b [134217728,  159383552)   w_in as bf16      (dead after gemm1)
  //   y_b    [100663296,  134217728)   overlays xb       (scan out, gemm2 in)
  //   w_out_b[134217728,  142606336)   overlays w_in_b   (converted after gemm1)
  char* ws = (char*)d_ws;
  unsigned short* z_b     = (unsigned short*)(ws);
  unsigned short* xb      = (unsigned short*)(ws + 100663296);
  unsigned short* w_in_b  = (unsigned short*)(ws + 134217728);
  unsigned short* y_b     = (unsigned short*)(ws + 100663296);
  unsigned short* w_out_b = (unsigned short*)(ws + 134217728);

  f2b4<<<16384, 256, 0, stream>>>(x,    xb,     4194304);
  f2b4<<<12288, 256, 0, stream>>>(w_in, w_in_b, 3145728);

  gemm_bt<true, unsigned short><<<dim3(48, 64), 256, 0, stream>>>(
      xb, w_in_b, b_in, z_b, 8192, 6144, 2048);

  f2b4<<<4096, 256, 0, stream>>>(w_out, w_out_b, 1048576);

  scan_kernel<<<32, 256, 0, stream>>>(z_b, conv_w, conv_b, sw, y_b);

  gemm_bt<false, float><<<dim3(16, 64), 256, 0, stream>>>(
      y_b, w_out_b, nullptr, out, 8192, 2048, 2048);
}

// Round 4
// 5846.467 us; speedup vs baseline: 1.0777x; 1.0777x over previous
//
#include <hip/hip_runtime.h>
#include <math.h>

#define B_   2
#define S_   4096
#define IN_  2048
#define ST_  2048
#define H_   16
#define D_   128
#define C3   6144   // 3*STATE

typedef __bf16 bf16x8 __attribute__((ext_vector_type(8)));
typedef float  f32x4  __attribute__((ext_vector_type(4)));

__device__ __forceinline__ float bf2f(unsigned short u) {
  union { unsigned int i; float f; } c; c.i = ((unsigned int)u) << 16; return c.f;
}
__device__ __forceinline__ unsigned short f2b_rtne(float f) {
  unsigned int x = __builtin_bit_cast(unsigned int, f);
  unsigned int r = (x + 0x7fffu + ((x >> 16) & 1u)) >> 16;
  return (unsigned short)r;
}
__device__ __forceinline__ float fast_sigmoid(float x) {
  return 1.0f / (1.0f + __expf(-x));
}
__device__ __forceinline__ float fast_tanh(float x) {
  float e = __expf(2.0f * x);
  return 1.0f - 2.0f / (e + 1.0f);
}

__device__ __forceinline__ void gload_lds16(const void* g, void* l) {
  __builtin_amdgcn_global_load_lds(
      (const __attribute__((address_space(1))) void*)g,
      (__attribute__((address_space(3))) void*)l, 16, 0, 0);
}

// ---------------- f32 -> bf16 convert ----------------
__global__ void f2b4(const float* __restrict__ in, unsigned short* __restrict__ out, int n4) {
  int i = blockIdx.x * 256 + threadIdx.x;
  if (i < n4) {
    f32x4 v = *(const f32x4*)(in + (size_t)i * 4);
    ushort4 o;
    o.x = f2b_rtne(v[0]); o.y = f2b_rtne(v[1]);
    o.z = f2b_rtne(v[2]); o.w = f2b_rtne(v[3]);
    *(ushort4*)(out + (size_t)i * 4) = o;
  }
}

// ---------------- bf16 GEMM: C[M][N] = A[M][K] * Bt[N][K]^T  (m97 structure) ----------------
template<bool TANH_BIAS, typename OutT>
__global__ __launch_bounds__(256, 2)
void gemm_bt(const unsigned short* __restrict__ A, const unsigned short* __restrict__ Bt,
             const float* __restrict__ bias, OutT* __restrict__ Cout,
             int M, int N, int K) {
  __shared__ __align__(16) unsigned short As[2][128 * 32];
  __shared__ __align__(16) unsigned short Bs[2][128 * 32];
  const int t    = threadIdx.x;
  const int wave = t >> 6, lane = t & 63;
  const int wm   = wave >> 1, wn = wave & 1;
  const int bm   = blockIdx.y * 128, bn = blockIdx.x * 128;

  auto stage = [&](int buf, int kt) {
#pragma unroll
    for (int p = 0; p < 2; ++p) {
      int unit = p * 256 + t;          // 16-byte unit, 512 units = 8KB tile
      int elem = unit * 8;             // bf16 element index
      int row  = elem >> 5;            // /32
      int col  = elem & 31;
      gload_lds16(A  + (size_t)(bm + row) * K + kt * 32 + col, &As[buf][elem]);
      gload_lds16(Bt + (size_t)(bn + row) * K + kt * 32 + col, &Bs[buf][elem]);
    }
  };

  f32x4 acc[4][4] = {};
  int cur = 0;
  stage(0, 0);
  __syncthreads();
  const int NT = K >> 5;
  for (int kt = 0; kt < NT; ++kt) {
    if (kt + 1 < NT) stage(cur ^ 1, kt + 1);
    const int kk = (lane >> 4) * 8;
    bf16x8 a[4], b[4];
#pragma unroll
    for (int m = 0; m < 4; ++m) {
      int row = wm * 64 + m * 16 + (lane & 15);
      a[m] = *(const bf16x8*)&As[cur][row * 32 + kk];
    }
#pragma unroll
    for (int n = 0; n < 4; ++n) {
      int col = wn * 64 + n * 16 + (lane & 15);
      b[n] = *(const bf16x8*)&Bs[cur][col * 32 + kk];
    }
#pragma unroll
    for (int m = 0; m < 4; ++m)
#pragma unroll
      for (int n = 0; n < 4; ++n)
        acc[m][n] = __builtin_amdgcn_mfma_f32_16x16x32_bf16(a[m], b[n], acc[m][n], 0, 0, 0);
    __syncthreads();
    cur ^= 1;
  }

#pragma unroll
  for (int n = 0; n < 4; ++n) {
    int col = bn + wn * 64 + n * 16 + (lane & 15);
    float bv = TANH_BIAS ? bias[col] : 0.0f;
#pragma unroll
    for (int m = 0; m < 4; ++m) {
      int row0 = bm + wm * 64 + m * 16 + (lane >> 4) * 4;
#pragma unroll
      for (int j = 0; j < 4; ++j) {
        float v = acc[m][n][j];
        if (TANH_BIAS) {
          v = fast_tanh(v + bv);
          ((unsigned short*)Cout)[(size_t)(row0 + j) * N + col] = f2b_rtne(v);
        } else {
          ((float*)Cout)[(size_t)(row0 + j) * N + col] = v;
        }
      }
    }
  }
}

// ---------------- fused conv + sequential GRU scan: one workgroup per (b,h) ----------------
// 512 threads (8 waves). Phase A: 256 gate outputs (r for o<128, f else), each computed
// by a thread PAIR (64-FMA halves + shfl_xor(1)) -> wA[64] regs/thread. Phase B: 128
// cand outputs, each by a thread QUAD (32-FMA quarters + 2 shfls) -> wB[32] regs/thread.
// Total weight regs/thread = 96 (fits; round-2's 192 spilled to scratch at VGPR=124 and
// cost 6x in scratch reloads). Conv K=4 fused as per-channel register sliding windows.
__global__ __launch_bounds__(512, 2)
void scan_kernel(const unsigned short* __restrict__ z,
                 const float* __restrict__ cw, const float* __restrict__ cb,
                 const float* __restrict__ sw,
                 unsigned short* __restrict__ y) {
  const int blk = blockIdx.x;       // 0..31
  const int b = blk >> 4, h = blk & 15;
  const int t = threadIdx.x;
  __shared__ __align__(16) float hS[128];
  __shared__ __align__(16) float rhS[128];
  __shared__ __align__(16) float fS[128];

  const float FAC = 1.0f / sqrtf(2176.0f);

  // ---- phase A assignment: output o in [0,256), pair-half sub ----
  const int o   = t >> 1;
  const int sub = t & 1;
  const bool isR = (o < 128);
  const int eA = isR ? o : (o - 128);
  const int gateM = isR ? (32 + h) : (16 + h);
  float wA[64];
  {
    const float* wp = sw + (size_t)gateM * (D_ * D_) + (size_t)(sub << 6) * 128 + eA;
#pragma unroll
    for (int d = 0; d < 64; ++d) wA[d] = wp[(size_t)d * 128] * FAC;
  }
  // ---- phase B assignment: output q in [0,128), quad-slot qs ----
  const int q  = t >> 2;
  const int qs = t & 3;
  float wB[32];
  {
    const float* wp = sw + (size_t)h * (D_ * D_) + (size_t)(qs << 5) * 128 + q;
#pragma unroll
    for (int j = 0; j < 32; ++j) wB[j] = wp[(size_t)j * 128] * FAC;
  }

  // conv taps + biases: gate channel (per pair) and i channel (per quad)
  const int chg = isR ? (2 * ST_ + h * 128 + eA) : (ST_ + h * 128 + eA);
  const int chi = h * 128 + q;
  const float cwg0 = cw[chg * 4 + 0], cwg1 = cw[chg * 4 + 1],
              cwg2 = cw[chg * 4 + 2], cwg3 = cw[chg * 4 + 3], cbg = cb[chg];
  const float cwi0 = cw[chi * 4 + 0], cwi1 = cw[chi * 4 + 1],
              cwi2 = cw[chi * 4 + 2], cwi3 = cw[chi * 4 + 3], cbi = cb[chi];

  const unsigned short* zg = z + (size_t)b * S_ * C3 + chg;
  const unsigned short* zi = z + (size_t)b * S_ * C3 + chi;
  unsigned short* yp = y + (size_t)b * S_ * ST_ + h * 128;

  // sliding windows: g3 = z[s], g2 = z[s-1], ...
  float g0 = 0.f, g1 = 0.f, g2 = 0.f, g3 = bf2f(zg[0]);
  float i0 = 0.f, i1 = 0.f, i2 = 0.f, i3 = bf2f(zi[0]);
  float gn  = bf2f(zg[C3]);   // z[1]
  float in_ = bf2f(zi[C3]);

  if (t < 128) hS[t] = 0.0f;
  __syncthreads();

  for (int st = 0; st < S_; ++st) {
    // prefetch z[st+2]
    float gnn = 0.f, inn = 0.f;
    if (st + 2 < S_) {
      gnn = bf2f(zg[(size_t)(st + 2) * C3]);
      inn = bf2f(zi[(size_t)(st + 2) * C3]);
    }
    const float gate_in = (g0 * cwg0 + g1 * cwg1 + g2 * cwg2 + g3 * cwg3 + cbg) * FAC;
    const float i_in    = (i0 * cwi0 + i1 * cwi1 + i2 * cwi2 + i3 * cwi3 + cbi) * FAC;

    // phase A: gate = sigmoid(gate_in + h . wA), pair-split over d
    {
      float s0 = 0.f, s1 = 0.f, s2 = 0.f, s3 = 0.f;
#pragma unroll
      for (int d = 0; d < 64; d += 4) {
        f32x4 hv = *(const f32x4*)&hS[(sub << 6) + d];
        s0 += hv[0] * wA[d + 0];
        s1 += hv[1] * wA[d + 1];
        s2 += hv[2] * wA[d + 2];
        s3 += hv[3] * wA[d + 3];
      }
      float dotA = (s0 + s1) + (s2 + s3);
      dotA += __shfl_xor(dotA, 1);
      float g = fast_sigmoid(dotA + gate_in);
      if (sub == 0) {
        if (isR) rhS[eA] = g * hS[eA];
        else     fS[eA]  = g;
      }
    }
    __syncthreads();

    // phase B: cand = tanh(i_in + (r*h) . wB), quad-split over d
    {
      float s0 = 0.f, s1 = 0.f, s2 = 0.f, s3 = 0.f;
#pragma unroll
      for (int j = 0; j < 32; j += 4) {
        f32x4 rv = *(const f32x4*)&rhS[(qs << 5) + j];
        s0 += rv[0] * wB[j + 0];
        s1 += rv[1] * wB[j + 1];
        s2 += rv[2] * wB[j + 2];
        s3 += rv[3] * wB[j + 3];
      }
      float dB = (s0 + s1) + (s2 + s3);
      dB += __shfl_xor(dB, 1);
      dB += __shfl_xor(dB, 2);
      float cand = fast_tanh(dB + i_in);
      if (qs == 0) {
        float f    = fS[q];
        float hOld = hS[q];
        float hNew = f * hOld + (1.0f - f) * cand;
        hS[q] = hNew;
        yp[(size_t)st * ST_ + q] = f2b_rtne(hNew);
      }
    }
    __syncthreads();

    g0 = g1; g1 = g2; g2 = g3; g3 = gn;  gn  = gnn;
    i0 = i1; i1 = i2; i2 = i3; i3 = in_; in_ = inn;
  }
}

extern "C" void kernel_launch(void* const* d_in, const int* in_sizes, int n_in,
                              void* d_out, int out_size, void* d_ws, size_t ws_size,
                              hipStream_t stream) {
  const float* x      = (const float*)d_in[0];
  const float* w_in   = (const float*)d_in[1];
  const float* b_in   = (const float*)d_in[2];
  const float* conv_w = (const float*)d_in[3];
  const float* conv_b = (const float*)d_in[4];
  const float* sw     = (const float*)d_in[5];
  const float* w_out  = (const float*)d_in[6];
  float* out = (float*)d_out;

  // Compact workspace layout (peak 152 MiB):
  //   z_b    [0,          100663296)   8192 x 6144 bf16  (gemm1 out, scan in)
  //   xb     [100663296,  134217728)   x as bf16         (dead after gemm1)
  //   w_in_b [134217728,  159383552)   w_in as bf16      (dead after gemm1)
  //   y_b    [100663296,  134217728)   overlays xb       (scan out, gemm2 in)
  //   w_out_b[134217728,  142606336)   overlays w_in_b   (converted after gemm1)
  char* ws = (char*)d_ws;
  unsigned short* z_b     = (unsigned short*)(ws);
  unsigned short* xb      = (unsigned short*)(ws + 100663296);
  unsigned short* w_in_b  = (unsigned short*)(ws + 134217728);
  unsigned short* y_b     = (unsigned short*)(ws + 100663296);
  unsigned short* w_out_b = (unsigned short*)(ws + 134217728);

  f2b4<<<16384, 256, 0, stream>>>(x,    xb,     4194304);
  f2b4<<<12288, 256, 0, stream>>>(w_in, w_in_b, 3145728);

  gemm_bt<true, unsigned short><<<dim3(48, 64), 256, 0, stream>>>(
      xb, w_in_b, b_in, z_b, 8192, 6144, 2048);

  f2b4<<<4096, 256, 0, stream>>>(w_out, w_out_b, 1048576);

  scan_kernel<<<32, 512, 0, stream>>>(z_b, conv_w, conv_b, sw, y_b);

  gemm_bt<false, float><<<dim3(16, 64), 256, 0, stream>>>(
      y_b, w_out_b, nullptr, out, 8192, 2048, 2048);
}

// Round 5
// 4536.041 us; speedup vs baseline: 1.3890x; 1.2889x over previous
//
#include <hip/hip_runtime.h>
#include <math.h>

#define B_   2
#define S_   4096
#define IN_  2048
#define ST_  2048
#define H_   16
#define D_   128
#define C3   6144   // 3*STATE

typedef __bf16 bf16x8 __attribute__((ext_vector_type(8)));
typedef short  short8 __attribute__((ext_vector_type(8)));
typedef float  f32x4  __attribute__((ext_vector_type(4)));

__device__ __forceinline__ float bf2f(unsigned short u) {
  union { unsigned int i; float f; } c; c.i = ((unsigned int)u) << 16; return c.f;
}
__device__ __forceinline__ unsigned short f2b_rtne(float f) {
  unsigned int x = __builtin_bit_cast(unsigned int, f);
  unsigned int r = (x + 0x7fffu + ((x >> 16) & 1u)) >> 16;
  return (unsigned short)r;
}
__device__ __forceinline__ float fast_sigmoid(float x) {
  return 1.0f / (1.0f + __expf(-x));
}
__device__ __forceinline__ float fast_tanh(float x) {
  float e = __expf(2.0f * x);
  return 1.0f - 2.0f / (e + 1.0f);
}

__device__ __forceinline__ void gload_lds16(const void* g, void* l) {
  __builtin_amdgcn_global_load_lds(
      (const __attribute__((address_space(1))) void*)g,
      (__attribute__((address_space(3))) void*)l, 16, 0, 0);
}

// ---------------- f32 -> bf16 convert ----------------
__global__ void f2b4(const float* __restrict__ in, unsigned short* __restrict__ out, int n4) {
  int i = blockIdx.x * 256 + threadIdx.x;
  if (i < n4) {
    f32x4 v = *(const f32x4*)(in + (size_t)i * 4);
    ushort4 o;
    o.x = f2b_rtne(v[0]); o.y = f2b_rtne(v[1]);
    o.z = f2b_rtne(v[2]); o.w = f2b_rtne(v[3]);
    *(ushort4*)(out + (size_t)i * 4) = o;
  }
}

// ---------------- bf16 GEMM: C[M][N] = A[M][K] * Bt[N][K]^T  (m97 structure) ----------------
template<bool TANH_BIAS, typename OutT>
__global__ __launch_bounds__(256, 2)
void gemm_bt(const unsigned short* __restrict__ A, const unsigned short* __restrict__ Bt,
             const float* __restrict__ bias, OutT* __restrict__ Cout,
             int M, int N, int K) {
  __shared__ __align__(16) unsigned short As[2][128 * 32];
  __shared__ __align__(16) unsigned short Bs[2][128 * 32];
  const int t    = threadIdx.x;
  const int wave = t >> 6, lane = t & 63;
  const int wm   = wave >> 1, wn = wave & 1;
  const int bm   = blockIdx.y * 128, bn = blockIdx.x * 128;

  auto stage = [&](int buf, int kt) {
#pragma unroll
    for (int p = 0; p < 2; ++p) {
      int unit = p * 256 + t;
      int elem = unit * 8;
      int row  = elem >> 5;
      int col  = elem & 31;
      gload_lds16(A  + (size_t)(bm + row) * K + kt * 32 + col, &As[buf][elem]);
      gload_lds16(Bt + (size_t)(bn + row) * K + kt * 32 + col, &Bs[buf][elem]);
    }
  };

  f32x4 acc[4][4] = {};
  int cur = 0;
  stage(0, 0);
  __syncthreads();
  const int NT = K >> 5;
  for (int kt = 0; kt < NT; ++kt) {
    if (kt + 1 < NT) stage(cur ^ 1, kt + 1);
    const int kk = (lane >> 4) * 8;
    bf16x8 a[4], b[4];
#pragma unroll
    for (int m = 0; m < 4; ++m) {
      int row = wm * 64 + m * 16 + (lane & 15);
      a[m] = *(const bf16x8*)&As[cur][row * 32 + kk];
    }
#pragma unroll
    for (int n = 0; n < 4; ++n) {
      int col = wn * 64 + n * 16 + (lane & 15);
      b[n] = *(const bf16x8*)&Bs[cur][col * 32 + kk];
    }
#pragma unroll
    for (int m = 0; m < 4; ++m)
#pragma unroll
      for (int n = 0; n < 4; ++n)
        acc[m][n] = __builtin_amdgcn_mfma_f32_16x16x32_bf16(a[m], b[n], acc[m][n], 0, 0, 0);
    __syncthreads();
    cur ^= 1;
  }

#pragma unroll
  for (int n = 0; n < 4; ++n) {
    int col = bn + wn * 64 + n * 16 + (lane & 15);
    float bv = TANH_BIAS ? bias[col] : 0.0f;
#pragma unroll
    for (int m = 0; m < 4; ++m) {
      int row0 = bm + wm * 64 + m * 16 + (lane >> 4) * 4;
#pragma unroll
      for (int j = 0; j < 4; ++j) {
        float v = acc[m][n][j];
        if (TANH_BIAS) {
          v = fast_tanh(v + bv);
          ((unsigned short*)Cout)[(size_t)(row0 + j) * N + col] = f2b_rtne(v);
        } else {
          ((float*)Cout)[(size_t)(row0 + j) * N + col] = v;
        }
      }
    }
  }
}

// ---------------- fused conv + MFMA GRU scan: one workgroup per (b,h) ----------------
// 512 threads = 8 waves. Weights live as named bf16x8 MFMA B-fragments in VGPRs
// (SSA values -> cannot be demoted to scratch like float[] arrays were in r2/r4).
// h is row-replicated into the A-fragment via 4 broadcast ds_read_b128 per wave, so
// every lane holds the full dot for col=lane&15 in acc[0] -> no shuffles/divergent
// reduce. Phase A: wave w owns gate outputs [32w,32w+32): waves 0-3 r-gate, 4-7
// f-gate (8 MFMAs each: 2 N-tiles x 4 K-tiles). Phase B: wave w owns cand cols
// [16w,16w+16) (4 MFMAs). Conv K=4 fused per-channel on threads 0..383, results
// passed through LDS. State h kept f32 in LDS; bf16 copy (hbS) feeds the MFMAs.
__global__ __launch_bounds__(512, 1)
void scan_kernel(const unsigned short* __restrict__ z,
                 const float* __restrict__ cw, const float* __restrict__ cb,
                 const float* __restrict__ sw,
                 unsigned short* __restrict__ y) {
  const int blk = blockIdx.x;       // 0..31
  const int b = blk >> 4, h = blk & 15;
  const int t = threadIdx.x;
  const int wave = t >> 6, lane = t & 63;
  const int kslot = (lane >> 4) * 8;    // k-offset within 32-wide K-tile
  const int col16 = lane & 15;

  __shared__ __align__(16) float hS[128];
  __shared__ __align__(16) float fS[128];
  __shared__ __align__(16) float gateinS[256];
  __shared__ __align__(16) float iinS[128];
  __shared__ __align__(16) unsigned short hbS[128];
  __shared__ __align__(16) unsigned short rhbS[128];

  const float FAC = 1.0f / sqrtf(2176.0f);

  // ---- weight B-fragments (loaded once, stay in VGPRs) ----
  const int mA  = (wave < 4) ? (32 + h) : (16 + h);  // r-matrix or f-matrix
  const int cA0 = (2 * wave) * 16 + col16;           // gate output index 0..255
  const int cA1 = cA0 + 16;
  const int eA0 = cA0 & 127, eA1 = cA1 & 127;        // element within matrix
  const int cB  = wave * 16 + col16;                 // cand col 0..127

  bf16x8 wa00, wa01, wa02, wa03, wa10, wa11, wa12, wa13, wb0, wb1, wb2, wb3;

#define LOADFRAG(dst, mat, colv, kt) { \
    const float* wp_ = sw + (size_t)(mat) * (D_ * D_) + (size_t)((kt) * 32 + kslot) * D_ + (colv); \
    short8 tmp_; \
    tmp_[0] = (short)f2b_rtne(wp_[0 * D_] * FAC); \
    tmp_[1] = (short)f2b_rtne(wp_[1 * D_] * FAC); \
    tmp_[2] = (short)f2b_rtne(wp_[2 * D_] * FAC); \
    tmp_[3] = (short)f2b_rtne(wp_[3 * D_] * FAC); \
    tmp_[4] = (short)f2b_rtne(wp_[4 * D_] * FAC); \
    tmp_[5] = (short)f2b_rtne(wp_[5 * D_] * FAC); \
    tmp_[6] = (short)f2b_rtne(wp_[6 * D_] * FAC); \
    tmp_[7] = (short)f2b_rtne(wp_[7 * D_] * FAC); \
    union { short8 s; bf16x8 v; } u_; u_.s = tmp_; dst = u_.v; }

  LOADFRAG(wa00, mA, eA0, 0) LOADFRAG(wa01, mA, eA0, 1)
  LOADFRAG(wa02, mA, eA0, 2) LOADFRAG(wa03, mA, eA0, 3)
  LOADFRAG(wa10, mA, eA1, 0) LOADFRAG(wa11, mA, eA1, 1)
  LOADFRAG(wa12, mA, eA1, 2) LOADFRAG(wa13, mA, eA1, 3)
  LOADFRAG(wb0,  h,  cB,  0) LOADFRAG(wb1,  h,  cB,  1)
  LOADFRAG(wb2,  h,  cB,  2) LOADFRAG(wb3,  h,  cB,  3)
#undef LOADFRAG

  // ---- conv channel assignment: t<256 -> gate channel t; t in [256,384) -> i channel ----
  const bool has_conv = (t < 384);
  int chan = 0;
  if (t < 256) chan = (t < 128) ? (2 * ST_ + h * 128 + t) : (ST_ + h * 128 + (t - 128));
  else if (t < 384) chan = h * 128 + (t - 256);
  float cw0 = 0.f, cw1 = 0.f, cw2 = 0.f, cw3 = 0.f, cbv = 0.f;
  if (has_conv) {
    cw0 = cw[chan * 4 + 0]; cw1 = cw[chan * 4 + 1];
    cw2 = cw[chan * 4 + 2]; cw3 = cw[chan * 4 + 3]; cbv = cb[chan];
  }
  const unsigned short* zp = z + (size_t)b * S_ * C3 + chan;
  unsigned short* yp = y + (size_t)b * S_ * ST_ + h * 128;

  // sliding window: w3_ = z[st], w2_ = z[st-1], ...
  float w0_ = 0.f, w1_ = 0.f, w2_ = 0.f, w3_ = 0.f, nx = 0.f;
  if (has_conv) { w3_ = bf2f(zp[0]); nx = bf2f(zp[C3]); }

  if (t < 128) { hS[t] = 0.0f; hbS[t] = 0; }
  __syncthreads();

  for (int st = 0; st < S_; ++st) {
    // prefetch z[st+2]
    float nn = 0.f;
    if (has_conv && st + 2 < S_) nn = bf2f(zp[(size_t)(st + 2) * C3]);
    // conv output for this step -> LDS
    if (has_conv) {
      float ci = (w0_ * cw0 + w1_ * cw1 + w2_ * cw2 + w3_ * cw3 + cbv) * FAC;
      if (t < 256) gateinS[t] = ci;
      else         iinS[t - 256] = ci;
    }

    // phase A MFMA: gate dots (h row-replicated A-fragment)
    f32x4 accA0 = {}, accA1 = {};
    {
      bf16x8 ha0 = *(const bf16x8*)&hbS[0 * 32 + kslot];
      bf16x8 ha1 = *(const bf16x8*)&hbS[1 * 32 + kslot];
      bf16x8 ha2 = *(const bf16x8*)&hbS[2 * 32 + kslot];
      bf16x8 ha3 = *(const bf16x8*)&hbS[3 * 32 + kslot];
      accA0 = __builtin_amdgcn_mfma_f32_16x16x32_bf16(ha0, wa00, accA0, 0, 0, 0);
      accA1 = __builtin_amdgcn_mfma_f32_16x16x32_bf16(ha0, wa10, accA1, 0, 0, 0);
      accA0 = __builtin_amdgcn_mfma_f32_16x16x32_bf16(ha1, wa01, accA0, 0, 0, 0);
      accA1 = __builtin_amdgcn_mfma_f32_16x16x32_bf16(ha1, wa11, accA1, 0, 0, 0);
      accA0 = __builtin_amdgcn_mfma_f32_16x16x32_bf16(ha2, wa02, accA0, 0, 0, 0);
      accA1 = __builtin_amdgcn_mfma_f32_16x16x32_bf16(ha2, wa12, accA1, 0, 0, 0);
      accA0 = __builtin_amdgcn_mfma_f32_16x16x32_bf16(ha3, wa03, accA0, 0, 0, 0);
      accA1 = __builtin_amdgcn_mfma_f32_16x16x32_bf16(ha3, wa13, accA1, 0, 0, 0);
    }
    __syncthreads();   // #1: conv LDS writes visible; hbS reads complete

    // epilogue A: gates; produce r*h (bf16) or stash f
    {
      float g0 = fast_sigmoid(accA0[0] + gateinS[cA0]);
      float g1 = fast_sigmoid(accA1[0] + gateinS[cA1]);
      if (wave < 4) {
        if (lane < 16) {
          rhbS[cA0] = f2b_rtne(g0 * hS[cA0]);
          rhbS[cA1] = f2b_rtne(g1 * hS[cA1]);
        }
      } else {
        if (lane < 16) { fS[eA0] = g0; fS[eA1] = g1; }
      }
    }
    __syncthreads();   // #2: rhbS / fS ready

    // phase B MFMA: cand dots + state update
    {
      f32x4 accB = {};
      bf16x8 ra0 = *(const bf16x8*)&rhbS[0 * 32 + kslot];
      bf16x8 ra1 = *(const bf16x8*)&rhbS[1 * 32 + kslot];
      bf16x8 ra2 = *(const bf16x8*)&rhbS[2 * 32 + kslot];
      bf16x8 ra3 = *(const bf16x8*)&rhbS[3 * 32 + kslot];
      accB = __builtin_amdgcn_mfma_f32_16x16x32_bf16(ra0, wb0, accB, 0, 0, 0);
      accB = __builtin_amdgcn_mfma_f32_16x16x32_bf16(ra1, wb1, accB, 0, 0, 0);
      accB = __builtin_amdgcn_mfma_f32_16x16x32_bf16(ra2, wb2, accB, 0, 0, 0);
      accB = __builtin_amdgcn_mfma_f32_16x16x32_bf16(ra3, wb3, accB, 0, 0, 0);
      float cand = fast_tanh(accB[0] + iinS[cB]);
      if (lane < 16) {
        float f    = fS[cB];
        float hOld = hS[cB];
        float hNew = f * hOld + (1.0f - f) * cand;
        hS[cB] = hNew;
        unsigned short hb = f2b_rtne(hNew);
        hbS[cB] = hb;
        yp[(size_t)st * ST_ + cB] = hb;
      }
    }
    __syncthreads();   // #3: hS/hbS ready for next step

    w0_ = w1_; w1_ = w2_; w2_ = w3_; w3_ = nx; nx = nn;
  }
}

extern "C" void kernel_launch(void* const* d_in, const int* in_sizes, int n_in,
                              void* d_out, int out_size, void* d_ws, size_t ws_size,
                              hipStream_t stream) {
  const float* x      = (const float*)d_in[0];
  const float* w_in   = (const float*)d_in[1];
  const float* b_in   = (const float*)d_in[2];
  const float* conv_w = (const float*)d_in[3];
  const float* conv_b = (const float*)d_in[4];
  const float* sw     = (const float*)d_in[5];
  const float* w_out  = (const float*)d_in[6];
  float* out = (float*)d_out;

  // Compact workspace layout (peak 152 MiB):
  //   z_b    [0,          100663296)   8192 x 6144 bf16  (gemm1 out, scan in)
  //   xb     [100663296,  134217728)   x as bf16         (dead after gemm1)
  //   w_in_b [134217728,  159383552)   w_in as bf16      (dead after gemm1)
  //   y_b    [100663296,  134217728)   overlays xb       (scan out, gemm2 in)
  //   w_out_b[134217728,  142606336)   overlays w_in_b   (converted after gemm1)
  char* ws = (char*)d_ws;
  unsigned short* z_b     = (unsigned short*)(ws);
  unsigned short* xb      = (unsigned short*)(ws + 100663296);
  unsigned short* w_in_b  = (unsigned short*)(ws + 134217728);
  unsigned short* y_b     = (unsigned short*)(ws + 100663296);
  unsigned short* w_out_b = (unsigned short*)(ws + 134217728);

  f2b4<<<16384, 256, 0, stream>>>(x,    xb,     4194304);
  f2b4<<<12288, 256, 0, stream>>>(w_in, w_in_b, 3145728);

  gemm_bt<true, unsigned short><<<dim3(48, 64), 256, 0, stream>>>(
      xb, w_in_b, b_in, z_b, 8192, 6144, 2048);

  f2b4<<<4096, 256, 0, stream>>>(w_out, w_out_b, 1048576);

  scan_kernel<<<32, 512, 0, stream>>>(z_b, conv_w, conv_b, sw, y_b);

  gemm_bt<false, float><<<dim3(16, 64), 256, 0, stream>>>(
      y_b, w_out_b, nullptr, out, 8192, 2048, 2048);
}